// Round 7
// baseline (56.921 us; speedup 1.0000x reference)
//
#include <hip/hip_runtime.h>

// YOLOv1 loss, MI355X. input/target (4096,14,14,30) f32 -> scalar f32 (loss/4096).
// Round 7: drop LDS staging entirely. Key fact: 30 dwords/cell is even, so
// aligned float2s never straddle a cell. One lane = one channel-pair; each wave
// processes 60 pairs (= exactly 4 cells) per iteration, so the channel-pair
// index j = lane%15 is a LOOP-INVARIANT per-lane constant. The j==0 lane holds
// the cell's (conf0,conf1) in its own target load -> computes the 3-way mask
// state and broadcasts it to its 15-lane group with one __shfl. No LDS, no
// barriers, no div/mod in the loop, perfectly coalesced 8 B/lane streaming.
// 7168 waves x 112 cells x 28 iters covers 802816 cells exactly.

#define COORD 5.0f
#define NOOBJ 0.5f

#define THREADS 256
#define GRID    1792                 // 7168 waves
#define ITERS   28                   // 60 pairs/iter -> 112 cells per wave

__global__ __launch_bounds__(THREADS) void yolo_loss_kernel(
    const float* __restrict__ inp,
    const float* __restrict__ tgt,
    float* __restrict__ out,
    float inv_n)
{
    __shared__ float wsum[THREADS / 64];

    const int tid  = threadIdx.x;
    const int lane = tid & 63;
    const int wv   = blockIdx.x * (THREADS / 64) + (tid >> 6);   // 0..7167

    const int l   = (lane < 60) ? lane : 59;   // clamp idle lanes onto lane 59's pair
    const int c15 = (l / 15) * 15;             // source lane holding this cell's conf pair
    const int j   = l - c15;                   // channel-pair index 0..14 (loop-invariant)
    const bool wh = (j == 2) || (j == 4);      // (w,h) pairs use sqrt-diff
    const float active = (lane < 60) ? 1.0f : 0.0f;

    // weights per state: s=1 (obj in slot0), s=2 (obj in slot1 only), s=0 (no obj)
    float wA0 = 0.f, wA1 = 0.f, wB0 = 0.f, wB1 = 0.f, wN0 = 0.f, wN1 = 0.f;
    if (j == 0)               { wA0 = 1.f; wB1 = 1.f; wN0 = NOOBJ; wN1 = NOOBJ; }
    else if (j == 1 || j == 2){ wA0 = wA1 = COORD; }
    else if (j == 3 || j == 4){ wB0 = wB1 = COORD; }
    else                      { wA0 = wA1 = wB0 = wB1 = 1.f; }   // classes

    const float2* ip2 = (const float2*)inp;
    const float2* tp2 = (const float2*)tgt;
    const size_t base = (size_t)wv * (60 * ITERS);

    float acc = 0.f;
#pragma unroll 4
    for (int i = 0; i < ITERS; ++i) {
        const size_t g = base + (size_t)i * 60 + l;
        float2 a = ip2[g];
        float2 b = tp2[g];

        // j==0 lanes see (conf0, conf1) of their cell; targets are exactly 0/1
        int s_mine = (b.x == 1.0f) ? 1 : ((b.y == 1.0f) ? 2 : 0);
        int s = __shfl(s_mine, c15, 64);

        float w0 = (s == 1) ? wA0 : ((s == 2) ? wB0 : wN0);
        float w1 = (s == 1) ? wA1 : ((s == 2) ? wB1 : wN1);

        float e0, e1;
        if (wh) {
            // (sqrt(a)-sqrt(b))^2 = a + b - 2*sqrt(a*b); inputs are uniforms >= 0
            e0 = a.x + b.x - 2.f * sqrtf(a.x * b.x);
            e1 = a.y + b.y - 2.f * sqrtf(a.y * b.y);
        } else {
            float d0 = a.x - b.x, d1 = a.y - b.y;
            e0 = d0 * d0;
            e1 = d1 * d1;
        }
        acc += w0 * e0 + w1 * e1;
    }
    acc *= active;   // lanes 60..63 duplicated lane 59's pair; zero them

    // ---- wave shfl reduce -> LDS -> one atomic per block ----
#pragma unroll
    for (int off = 32; off > 0; off >>= 1)
        acc += __shfl_down(acc, off, 64);
    if (lane == 0) wsum[tid >> 6] = acc;
    __syncthreads();
    if (tid == 0)
        atomicAdd(out, (wsum[0] + wsum[1] + wsum[2] + wsum[3]) * inv_n);
}

extern "C" void kernel_launch(void* const* d_in, const int* in_sizes, int n_in,
                              void* d_out, int out_size, void* d_ws, size_t ws_size,
                              hipStream_t stream) {
    const float* inp = (const float*)d_in[0];
    const float* tgt = (const float*)d_in[1];
    float* out = (float*)d_out;

    hipMemsetAsync(out, 0, sizeof(float), stream);
    yolo_loss_kernel<<<GRID, THREADS, 0, stream>>>(inp, tgt, out, 1.0f / 4096.0f);
}